// Round 1
// baseline (138.597 us; speedup 1.0000x reference)
//
#include <hip/hip_runtime.h>

// Problem constants (from reference): B=64, OH=120, OW=160, THRESHOLD=0.5
#define OW_   160
#define OH_   120
#define HW_   (OH_ * OW_)          // 19200  (divisible by 256 -> blocks never span batches)
#define BATCH 64
#define NPIX  (BATCH * HW_)        // 1228800
#define BLK   256

// Output layout in d_out (flat, return order):
//   boxes     [NPIX*5]   at offset 0
//   landmarks [NPIX*10]  at offset NPIX*5
//   keep      [NPIX]     at offset NPIX*15
#define BOX_OFF 0
#define LM_OFF  ((size_t)NPIX * 5)
#define KEEP_OFF ((size_t)NPIX * 15)

__global__ __launch_bounds__(BLK) void detpost_kernel(
    const float* __restrict__ heatmap,   // [B,1,H,W]
    const float* __restrict__ scale,     // [B,2,H,W]
    const float* __restrict__ offset,    // [B,2,H,W]
    const float* __restrict__ landmark,  // [B,10,H,W]
    float* __restrict__ boxes,           // [B*HW,5]
    float* __restrict__ lms,             // [B*HW,10]
    float* __restrict__ keepo)           // [B*HW]
{
    __shared__ float sbox[BLK * 5];      // 5 KB
    __shared__ float slm [BLK * 10];     // 10 KB

    const int tid = threadIdx.x;
    const int idx = blockIdx.x * BLK + tid;   // global pixel index (b*HW + p)
    const int b   = idx / HW_;
    const int p   = idx - b * HW_;
    const int h   = p / OW_;                  // row within the heatmap

    // ---- coalesced channel-planar loads ----
    const float s    = heatmap[idx];
    const float* scb = scale  + (size_t)b * 2 * HW_;
    const float sc0  = scb[p];
    const float sc1  = scb[HW_ + p];
    const float off0 = offset[(size_t)b * 2 * HW_ + p];   // offset channel 1 is unused by the reference

    // ---- per-pixel math (fp32, matches reference) ----
    const float s0 = __expf(sc0) * 4.0f;
    const float s1 = __expf(sc1) * 4.0f;
    const float y1raw = ((float)h + off0 + 0.5f) * 4.0f - s0 * 0.5f;
    const float y1c = fmaxf(y1raw, 0.0f);
    const float y1  = fminf(y1c, 480.0f);     // in_h = OH*4
    const float x1  = fminf(y1c, 640.0f);     // in_w = OW*4  (yes, from y1c — reference quirk)
    const float y2  = fminf(y1 + s0, 480.0f);
    const float x2  = fminf(x1 + s1, 640.0f);

    const bool keep = (s >= 0.5f);

    // ---- stage boxes tile in LDS (stride 5 -> 2-way bank alias, free) ----
    sbox[tid * 5 + 0] = keep ? x1 : 0.0f;
    sbox[tid * 5 + 1] = keep ? y1 : 0.0f;
    sbox[tid * 5 + 2] = keep ? x2 : 0.0f;
    sbox[tid * 5 + 3] = keep ? y2 : 0.0f;
    sbox[tid * 5 + 4] = keep ? s  : 0.0f;

    // ---- landmarks: even channels use (s0,y1), odd use (s1,x1) ----
    const float* lmb = landmark + (size_t)b * 10 * HW_ + p;
#pragma unroll
    for (int c = 0; c < 10; ++c) {
        const float lv = lmb[(size_t)c * HW_];
        const float v  = (c & 1) ? fmaf(lv, s1, x1) : fmaf(lv, s0, y1);
        slm[tid * 10 + c] = keep ? v : 0.0f;
    }

    // keep mask: already output-linear, store directly
    keepo[idx] = keep ? 1.0f : 0.0f;

    __syncthreads();

    // ---- coalesced float4 stores from LDS (output-linear) ----
    // boxes: 256*5 = 1280 floats = 320 float4 per block; block base = blockIdx*5120 B (16-aligned)
    {
        const float4* sb4 = (const float4*)sbox;
        float4* gb4 = (float4*)(boxes + (size_t)blockIdx.x * (BLK * 5));
#pragma unroll
        for (int j = tid; j < BLK * 5 / 4; j += BLK) gb4[j] = sb4[j];
    }
    // landmarks: 256*10 = 2560 floats = 640 float4 per block
    {
        const float4* sl4 = (const float4*)slm;
        float4* gl4 = (float4*)(lms + (size_t)blockIdx.x * (BLK * 10));
#pragma unroll
        for (int j = tid; j < BLK * 10 / 4; j += BLK) gl4[j] = sl4[j];
    }
}

extern "C" void kernel_launch(void* const* d_in, const int* in_sizes, int n_in,
                              void* d_out, int out_size, void* d_ws, size_t ws_size,
                              hipStream_t stream) {
    const float* heatmap  = (const float*)d_in[0];
    const float* scale    = (const float*)d_in[1];
    const float* offset   = (const float*)d_in[2];
    const float* landmark = (const float*)d_in[3];

    float* out   = (float*)d_out;
    float* boxes = out + BOX_OFF;
    float* lms   = out + LM_OFF;
    float* keepo = out + KEEP_OFF;

    const int nblocks = NPIX / BLK;   // 4800, exact
    detpost_kernel<<<nblocks, BLK, 0, stream>>>(heatmap, scale, offset, landmark,
                                                boxes, lms, keepo);
}